// Round 6
// baseline (440.658 us; speedup 1.0000x reference)
//
#include <hip/hip_runtime.h>
#include <hip/hip_fp16.h>

// ---------------------------------------------------------------------------
// GCN (3 layers) + global mean pool + linear, fp32 in/out, MI355X.
// t'[i] = dinv[i] * h[i] W^T; h_next[i] = relu(dinv[i]*(t'[i]+sum t'[j]) + b)
// R3-R5: scattered 4B global stores/atomics = ~32B HBM sector each. Dense only.
// R9: fp16 t (128B row = 1 L2 line), absmax 1.2e-4.
// R13/R18/R20: agg must keep ~1 node/wave (50000 waves); W must be amortized.
// R21: 8-wide masked slice gather; aggfinal fuses agg3+pool+linear.
// R22-R24 (counter-verified NULL ladder, all 58-61us): group-owns-whole-list
//   gather at 12504 waves, then shfl-broadcast (R23), then forced reg-window
//   (R24) -- VGPR stuck at 52: compiler refuses >~8-deep load windows at HIP
//   level. ILP-window lever is DEAD. Cross-kernel A/B: aggfinal (1 node/wave,
//   ~2 serial phases) < 44us vs aggmm gather ~49us -> phases/wave x loaded
//   latency governs.
// R25 (this round): (1) aggmm gather back to 1-node-per-WAVE slice form
//   (8 nodes per 512-thr block, 50000 gather waves, ~2 phases); mm keeps W
//   amortized per block, dv wave-uniform. (2) Software L2 tiling: gather in
//   2 source-half passes (3.2MB half < 4MB XCD-L2); out-of-half edges clamp
//   to 'lo' + mask-FMA -> ~96% of row-gathers become L2 hits. Signature:
//   FETCH_SIZE UP (8-XCD compulsory refills x 2), time DOWN.
//   aggfinal left untouched as control.
// ---------------------------------------------------------------------------

#define CAPB 3072
#define BINTILE 4096

// fctr zero + per-graph inverse counts (binary search on sorted batch) +
// out seeded with bl (aggfinal accumulates atomically on top).
__global__ __launch_bounds__(256) void init_kernel(int* __restrict__ fctr,
                                                   const int* __restrict__ batch,
                                                   const float* __restrict__ bl,
                                                   float* __restrict__ invc,
                                                   float* __restrict__ out,
                                                   int n, int nb) {
    int t = blockIdx.x * blockDim.x + threadIdx.x;
    if (t < 512) fctr[t] = 0;
    if (t < nb) {
        int l = 0, r = n;
        while (l < r) { int m = (l + r) >> 1; if (batch[m] < t) l = m + 1; else r = m; }
        int lo = l;
        r = n;
        while (l < r) { int m = (l + r) >> 1; if (batch[m] < t + 1) l = m + 1; else r = m; }
        invc[t] = 1.0f / fmaxf((float)(l - lo), 1.0f);
#pragma unroll
        for (int o = 0; o < 16; ++o) out[t * 16 + o] = bl[o];
    }
}

// Bucket edges into 512 fine dst-ranges (fixed capacity CAPB, base=g*CAPB).
__global__ __launch_bounds__(256) void bin512_kernel(const int* __restrict__ src,
                                                     const int* __restrict__ dst,
                                                     int* __restrict__ fctr,
                                                     int2* __restrict__ recs2,
                                                     int e, int n) {
    __shared__ int lcnt[512], gbase[512];
    int tid = threadIdx.x;
    int s0  = blockIdx.x * BINTILE;
    lcnt[tid] = 0;
    lcnt[tid + 256] = 0;
    __syncthreads();
    int dv[16], bk[16];
#pragma unroll
    for (int k = 0; k < 16; ++k) {
        int i = s0 + tid + k * 256;  // coalesced
        if (i < e) {
            dv[k] = dst[i];
            bk[k] = (int)((512LL * dv[k]) / n);
            atomicAdd(&lcnt[bk[k]], 1);
        } else {
            bk[k] = -1;
        }
    }
    __syncthreads();
#pragma unroll
    for (int j = 0; j < 2; ++j) {
        int b = tid + j * 256;
        gbase[b] = b * CAPB + atomicAdd(&fctr[b], lcnt[b]);
        lcnt[b]  = 0;  // reuse as placement counter
    }
    __syncthreads();
#pragma unroll
    for (int k = 0; k < 16; ++k) {
        if (bk[k] >= 0) {
            int i = s0 + tid + k * 256;
            int p = gbase[bk[k]] + atomicAdd(&lcnt[bk[k]], 1);
            if (p < (bk[k] + 1) * CAPB) recs2[p] = make_int2(src[i], dv[k]);
        }
    }
}

// One block per fine bucket: LDS counting sort -> dense csr, rp/dinv, then
// fused mm1 for this bucket's nodes: t1 = fp16(dinv * x W1^T).
__global__ __launch_bounds__(256) void sortfill_mm_kernel(
    const int2* __restrict__ recs2, const int* __restrict__ fctr,
    int* __restrict__ rp, float* __restrict__ dinv, int* __restrict__ csr,
    const float* __restrict__ x, const float* __restrict__ W1,
    __half* __restrict__ t1, int n) {
    __shared__ int hist[128];
    __shared__ int lofs[129];
    __shared__ int stage[CAPB];
    __shared__ int redbuf[256];
    __shared__ float xrow[98 * 64];  // 25KB
    int g   = blockIdx.x;
    int N0  = (int)(((long long)n * g + 511) / 512);
    int N1  = (int)(((long long)n * (g + 1) + 511) / 512);
    int nn  = N1 - N0;  // <= 98
    int tid = threadIdx.x;
    int lane = tid & 63;
    int wave = tid >> 6;

    int partial = 0;
    for (int j = tid; j < g; j += 256) partial += min(fctr[j], CAPB);
    redbuf[tid] = partial;
    if (tid < 128) hist[tid] = 0;
    __syncthreads();
    for (int s = 128; s > 0; s >>= 1) {
        if (tid < s) redbuf[tid] += redbuf[tid + s];
        __syncthreads();
    }
    int base = redbuf[0];
    const int2* my = recs2 + (size_t)g * CAPB;
    int total = min(fctr[g], CAPB);
    for (int i = tid; i < total; i += 256)
        atomicAdd(&hist[my[i].y - N0], 1);
    __syncthreads();
    if (tid == 0) {
        int acc = 0;
        for (int k = 0; k < nn; ++k) { lofs[k] = acc; acc += hist[k]; }
        lofs[nn] = acc;
    }
    __syncthreads();
    if (tid < 128) hist[tid] = 0;  // placement counters
    __syncthreads();
    for (int i = tid; i < total; i += 256) {
        int2 rec = my[i];
        int  li  = rec.y - N0;
        int  pos = lofs[li] + atomicAdd(&hist[li], 1);
        stage[pos] = rec.x;  // pos < total <= CAPB
    }
    __syncthreads();
    for (int j = tid; j < total; j += 256) csr[base + j] = stage[j];
    if (tid < nn) {
        rp[N0 + tid]   = base + lofs[tid];
        int deg        = lofs[tid + 1] - lofs[tid];
        dinv[N0 + tid] = rsqrtf((float)(deg + 1));
    }
    if (g == 511 && tid == 0) rp[n] = base + total;

    // ---- fused mm1 for this bucket's nodes ----
    for (int idx = tid; idx < nn * 16; idx += 256)
        ((float4*)xrow)[idx] = ((const float4*)(x + (size_t)N0 * 64))[idx];
    float4 wreg[16];
    const float4* W4 = (const float4*)(W1 + lane * 64);
#pragma unroll
    for (int q = 0; q < 16; ++q) wreg[q] = W4[q];
    __syncthreads();
    for (int li = wave; li < nn; li += 4) {
        float dv = rsqrtf((float)(lofs[li + 1] - lofs[li] + 1));
        const float4* row = (const float4*)(xrow + li * 64);
        float acc = 0.0f;
#pragma unroll
        for (int q = 0; q < 16; ++q) {
            float4 hv = row[q];  // wave-uniform -> LDS broadcast
            acc += hv.x * wreg[q].x + hv.y * wreg[q].y +
                   hv.z * wreg[q].z + hv.w * wreg[q].w;
        }
        t1[(size_t)(N0 + li) * 64 + lane] = __float2half(acc * dv);
    }
}

// Fused agg(layer k) + mm(layer k+1): 512 thr = 8 waves = 8 NODES per block
// (1 node/WAVE -> 50000 gather waves, the R13/R18 invariant). Gather is the
// R21-proven 4-group slice (deg/4 per group, 8-wide clamped mask-FMA),
// wrapped in a 2-pass SOURCE-HALF loop: each 3.2MB half of t is XCD-L2
// resident during its pass; out-of-half edges clamp to 'lo' and mask to 0.
// shfl_xor(16,32) reduce -> grp0 writes h row to LDS; mm phase reads h rows
// broadcast vs W row per lane (16 float4 regs), dv wave-uniform.
__global__ __launch_bounds__(512, 4) void aggmm_kernel(const __half* __restrict__ t,
                                                       const int* __restrict__ rp,
                                                       const int* __restrict__ cs,
                                                       const float* __restrict__ dinv,
                                                       const float* __restrict__ bias,
                                                       const float* __restrict__ W,
                                                       __half* __restrict__ tout, int n) {
    __shared__ float hs[8 * 64];  // 2KB
    int tid  = threadIdx.x;
    int lane = tid & 63;
    int wave = tid >> 6;        // 0..7 = local node
    int grp  = lane >> 4;
    int fo   = (lane & 15) << 2;
    int base = blockIdx.x * 8;
    int i    = base + wave;
    int ii   = min(i, n - 1);   // tail-block clamp; stores guarded by i<n

    int beg = rp[ii];
    int end = rp[ii + 1];
    int deg = end - beg;

    // independent early loads
    uint2 su = *(const uint2*)(t + (size_t)ii * 64 + fo);
    float dv = dinv[ii];
    float4 bv = *(const float4*)(bias + fo);

    int len = (deg + 3) >> 2;       // per-group slice
    int gb  = beg + grp * len;
    int ge  = min(gb + len, end);

    float4 aa[4];
    aa[0] = make_float4(0.f, 0.f, 0.f, 0.f);
    aa[1] = aa[0]; aa[2] = aa[0]; aa[3] = aa[0];

    int hn = (n + 1) >> 1;          // 25000 -> 3.2MB fp16 half
#pragma unroll
    for (int hf = 0; hf < 2; ++hf) {
        int lo = hf * hn;
        int hi = min(lo + hn, n);
        for (int eb = gb; eb < ge; eb += 8) {
#pragma unroll
            for (int j = 0; j < 8; ++j) {
                int  ej = eb + j;
                int  ec = min(ej, end - 1);          // in csr bounds (deg>=0 ok: beg<=ec)
                int  sj = cs[ec];                    // unconditional, coalesced-ish
                bool ok = (ej < ge) && (sj >= lo) && (sj < hi);
                int  sc = ok ? sj : lo;              // clamp into resident half
                uint2 u  = *(const uint2*)(t + (size_t)sc * 64 + fo);
                float m  = ok ? 1.0f : 0.0f;
                float2 f0 = __half22float2(*(const __half2*)&u.x);
                float2 f1 = __half22float2(*(const __half2*)&u.y);
                aa[j & 3].x = fmaf(m, f0.x, aa[j & 3].x);
                aa[j & 3].y = fmaf(m, f0.y, aa[j & 3].y);
                aa[j & 3].z = fmaf(m, f1.x, aa[j & 3].z);
                aa[j & 3].w = fmaf(m, f1.y, aa[j & 3].w);
            }
        }
    }
    float4 acc;
    acc.x = (aa[0].x + aa[1].x) + (aa[2].x + aa[3].x);
    acc.y = (aa[0].y + aa[1].y) + (aa[2].y + aa[3].y);
    acc.z = (aa[0].z + aa[1].z) + (aa[2].z + aa[3].z);
    acc.w = (aa[0].w + aa[1].w) + (aa[2].w + aa[3].w);
    acc.x += __shfl_xor(acc.x, 16, 64);
    acc.y += __shfl_xor(acc.y, 16, 64);
    acc.z += __shfl_xor(acc.z, 16, 64);
    acc.w += __shfl_xor(acc.w, 16, 64);
    acc.x += __shfl_xor(acc.x, 32, 64);
    acc.y += __shfl_xor(acc.y, 32, 64);
    acc.z += __shfl_xor(acc.z, 32, 64);
    acc.w += __shfl_xor(acc.w, 32, 64);

    if (grp == 0 && i < n) {
        float2 s01 = __half22float2(*(const __half2*)&su.x);
        float2 s23 = __half22float2(*(const __half2*)&su.y);
        float4 h4;
        h4.x = fmaxf(fmaf(dv, acc.x + s01.x, bv.x), 0.0f);
        h4.y = fmaxf(fmaf(dv, acc.y + s01.y, bv.y), 0.0f);
        h4.z = fmaxf(fmaf(dv, acc.z + s23.x, bv.z), 0.0f);
        h4.w = fmaxf(fmaf(dv, acc.w + s23.y, bv.w), 0.0f);
        *(float4*)(hs + wave * 64 + fo) = h4;
    }
    __syncthreads();

    // ---- mm phase: wave computes its OWN node's output row (dv uniform) ----
    float4 wreg[16];
    const float4* W4 = (const float4*)(W + lane * 64);
#pragma unroll
    for (int q = 0; q < 16; ++q) wreg[q] = W4[q];  // L1-resident after 1st block
    if (i < n) {
        const float4* row = (const float4*)(hs + wave * 64);
        float acc2 = 0.0f;
#pragma unroll
        for (int q = 0; q < 16; ++q) {
            float4 hv = row[q];  // wave-uniform address -> LDS broadcast
            acc2 += hv.x * wreg[q].x + hv.y * wreg[q].y +
                    hv.z * wreg[q].z + hv.w * wreg[q].w;
        }
        tout[(size_t)i * 64 + lane] = __float2half(acc2 * dv);
    }
}

// Final layer (CONTROL — unchanged from R24): slice gather, batch-then-
// consume -> h3 on all lanes -> z = h3 . Wl^T chunk-parallel, xor-reduce,
// 16 atomicAdds of z*inv_cnt into bl-seeded out.
__global__ __launch_bounds__(256, 6) void aggfinal_kernel(const __half* __restrict__ t,
                                                          const int* __restrict__ rp,
                                                          const int* __restrict__ cs,
                                                          const float* __restrict__ dinv,
                                                          const float* __restrict__ bias,
                                                          const float* __restrict__ Wl,
                                                          const int* __restrict__ batch,
                                                          const float* __restrict__ invc,
                                                          float* __restrict__ out, int n) {
    int gw   = (blockIdx.x * blockDim.x + threadIdx.x) >> 6;
    int lane = threadIdx.x & 63;
    if (gw >= n) return;
    int i   = gw;
    int grp = lane >> 4;
    int fo  = (lane & 15) << 2;
    int beg = rp[i];
    int end = rp[i + 1];
    uint2 su = *(const uint2*)(t + (size_t)i * 64 + fo);
    float dv = dinv[i];
    float4 bv = *(const float4*)(bias + fo);

    int deg = end - beg;
    int len = (deg + 3) >> 2;
    int gb  = beg + grp * len;
    int ge  = min(gb + len, end);

    float4 aa[4];
    aa[0] = make_float4(0.f, 0.f, 0.f, 0.f);
    aa[1] = aa[0]; aa[2] = aa[0]; aa[3] = aa[0];
    for (int eb = gb; eb < ge; eb += 8) {
        int sjv[8];
#pragma unroll
        for (int j = 0; j < 8; ++j) sjv[j] = cs[min(eb + j, end - 1)];
        uint2 ub[8];
#pragma unroll
        for (int j = 0; j < 8; ++j)
            ub[j] = *(const uint2*)(t + (size_t)sjv[j] * 64 + fo);
        __builtin_amdgcn_sched_barrier(0);
#pragma unroll
        for (int j = 0; j < 8; ++j) {
            float m  = (eb + j < ge) ? 1.0f : 0.0f;
            float2 f0 = __half22float2(*(const __half2*)&ub[j].x);
            float2 f1 = __half22float2(*(const __half2*)&ub[j].y);
            aa[j & 3].x = fmaf(m, f0.x, aa[j & 3].x);
            aa[j & 3].y = fmaf(m, f0.y, aa[j & 3].y);
            aa[j & 3].z = fmaf(m, f1.x, aa[j & 3].z);
            aa[j & 3].w = fmaf(m, f1.y, aa[j & 3].w);
        }
    }
    float4 acc;
    acc.x = (aa[0].x + aa[1].x) + (aa[2].x + aa[3].x);
    acc.y = (aa[0].y + aa[1].y) + (aa[2].y + aa[3].y);
    acc.z = (aa[0].z + aa[1].z) + (aa[2].z + aa[3].z);
    acc.w = (aa[0].w + aa[1].w) + (aa[2].w + aa[3].w);
    acc.x += __shfl_xor(acc.x, 16, 64);
    acc.y += __shfl_xor(acc.y, 16, 64);
    acc.z += __shfl_xor(acc.z, 16, 64);
    acc.w += __shfl_xor(acc.w, 16, 64);
    acc.x += __shfl_xor(acc.x, 32, 64);
    acc.y += __shfl_xor(acc.y, 32, 64);
    acc.z += __shfl_xor(acc.z, 32, 64);
    acc.w += __shfl_xor(acc.w, 32, 64);

    // all lanes hold h3[i][4*(lane&15) .. +3]
    float2 s01 = __half22float2(*(const __half2*)&su.x);
    float2 s23 = __half22float2(*(const __half2*)&su.y);
    float4 h4;
    h4.x = fmaxf(fmaf(dv, acc.x + s01.x, bv.x), 0.0f);
    h4.y = fmaxf(fmaf(dv, acc.y + s01.y, bv.y), 0.0f);
    h4.z = fmaxf(fmaf(dv, acc.z + s23.x, bv.z), 0.0f);
    h4.w = fmaxf(fmaf(dv, acc.w + s23.y, bv.w), 0.0f);

    // z[o] = h3 . Wl[o], o = 4m + grp; lane uses only its own chunk.
    float4 wl0 = *(const float4*)(Wl + (0 * 4 + grp) * 64 + fo);
    float4 wl1 = *(const float4*)(Wl + (1 * 4 + grp) * 64 + fo);
    float4 wl2 = *(const float4*)(Wl + (2 * 4 + grp) * 64 + fo);
    float4 wl3 = *(const float4*)(Wl + (3 * 4 + grp) * 64 + fo);
    float z0 = h4.x * wl0.x + h4.y * wl0.y + h4.z * wl0.z + h4.w * wl0.w;
    float z1 = h4.x * wl1.x + h4.y * wl1.y + h4.z * wl1.z + h4.w * wl1.w;
    float z2 = h4.x * wl2.x + h4.y * wl2.y + h4.z * wl2.z + h4.w * wl2.w;
    float z3 = h4.x * wl3.x + h4.y * wl3.y + h4.z * wl3.z + h4.w * wl3.w;
#pragma unroll
    for (int s = 1; s <= 8; s <<= 1) {
        z0 += __shfl_xor(z0, s, 64);
        z1 += __shfl_xor(z1, s, 64);
        z2 += __shfl_xor(z2, s, 64);
        z3 += __shfl_xor(z3, s, 64);
    }
    int m = lane & 15;
    if (m < 4) {
        int   b  = batch[i];
        float ic = invc[b];
        float zv = (m == 0) ? z0 : (m == 1) ? z1 : (m == 2) ? z2 : z3;
        atomicAdd(out + b * 16 + (m * 4 + grp), zv * ic);
    }
}

extern "C" void kernel_launch(void* const* d_in, const int* in_sizes, int n_in,
                              void* d_out, int out_size, void* d_ws, size_t ws_size,
                              hipStream_t stream) {
    const float* x    = (const float*)d_in[0];
    const int*   ei   = (const int*)d_in[1];
    const int*   batch= (const int*)d_in[2];
    const float* W1   = (const float*)d_in[3];
    const float* b1   = (const float*)d_in[4];
    const float* W2   = (const float*)d_in[5];
    const float* b2   = (const float*)d_in[6];
    const float* W3   = (const float*)d_in[7];
    const float* b3   = (const float*)d_in[8];
    const float* Wl   = (const float*)d_in[9];
    const float* bl   = (const float*)d_in[10];
    float* out = (float*)d_out;

    int n  = in_sizes[0] / 64;   // 50000 nodes
    int e  = in_sizes[1] / 2;    // 1250000 edges
    int nb = out_size / 16;      // 512 graphs

    const int* esrc = ei;
    const int* edst = ei + e;

    char* p = (char*)d_ws;
    auto carve = [&](size_t bytes) {
        char* r = p;
        p += (bytes + 255) & ~(size_t)255;
        return r;
    };
    float*  dinv  = (float*)carve((size_t)n * 4);
    int*    rp    = (int*)  carve((size_t)(n + 1) * 4);
    int*    csr   = (int*)  carve((size_t)e * 4);
    __half* tA    = (__half*)carve((size_t)n * 64 * 2);  // t1 / t3
    __half* tB    = (__half*)carve((size_t)n * 64 * 2);  // t2
    int2*   recs2 = (int2*) carve((size_t)512 * CAPB * 8);
    int*    fctr  = (int*)  carve(512 * 4);
    float*  invc  = (float*)carve((size_t)nb * 4);

    dim3 blk(256);
    int gBIN = (e + BINTILE - 1) / BINTILE;  // 306 tiles
    int gFUS = (n + 7) / 8;                  // 8 nodes / 512-thr block (1/wave)
    int gAGG = (n + 3) / 4;                  // one node per wave (aggfinal)

    init_kernel<<<2, blk, 0, stream>>>(fctr, batch, bl, invc, out, n, nb);
    bin512_kernel<<<gBIN, blk, 0, stream>>>(esrc, edst, fctr, recs2, e, n);
    sortfill_mm_kernel<<<512, blk, 0, stream>>>(recs2, fctr, rp, dinv, csr,
                                                x, W1, tA, n);
    aggmm_kernel<<<gFUS, dim3(512), 0, stream>>>(tA, rp, csr, dinv, b1, W2, tB, n);
    aggmm_kernel<<<gFUS, dim3(512), 0, stream>>>(tB, rp, csr, dinv, b2, W3, tA, n);
    aggfinal_kernel<<<gAGG, blk, 0, stream>>>(tA, rp, csr, dinv, b3, Wl,
                                              batch, invc, out, n);
}

// Round 7
// 399.369 us; speedup vs baseline: 1.1034x; 1.1034x over previous
//
#include <hip/hip_runtime.h>
#include <hip/hip_fp16.h>

// ---------------------------------------------------------------------------
// GCN (3 layers) + global mean pool + linear, fp32 in/out, MI355X.
// t'[i] = dinv[i] * h[i] W^T; h_next[i] = relu(dinv[i]*(t'[i]+sum t'[j]) + b)
// R3-R5: scattered 4B global stores/atomics = ~32B HBM sector each. Dense only.
// R9: fp16 t (128B row = 1 L2 line), absmax 1.2e-4.
// R13/R18/R20: agg needs ~50000 gather waves; W-in-regs can't be forced
//   (compiler refuses >8-deep load windows / 64-reg W arrays; R20/R23/R24).
// R21: 8-wide masked slice gather (proven <=44us standalone at (256,6)).
// R22-R24: fused aggmm at 1563x512 blocks = 58-61us (occupancy 33%, grid too
//   coarse). ILP-window ladder NULL (VGPR stuck ~52).
// R25: 2-pass L2 half-tiling FAILED (137.9us): loads doubled, FETCH_SIZE flat
//   (43MB of 160MB traffic -> already 74% cache-absorbed; not miss-bound).
//   KEY LEAK: 6250-block 1-node-per-wave grid hit 61% occupancy (vs 33%).
// R26 (this round): R25's parallelism + R21's single-pass gather + fused mm:
//   512 thr = 8 waves = 8 nodes/block (1 node/WAVE, 6250 blocks), 4-group
//   slice gather (deg/4 per group, 8-wide clamped mask-FMA, ~2 latency
//   phases), shfl_xor reduce, grp0 -> LDS h row; per-wave mm (W reload from
//   L1 is fine at this TLP, dv wave-uniform). aggfinal/bin/sortfill = 285.98
//   controls.
// ---------------------------------------------------------------------------

#define CAPB 3072
#define BINTILE 4096

// fctr zero + per-graph inverse counts (binary search on sorted batch) +
// out seeded with bl (aggfinal accumulates atomically on top).
__global__ __launch_bounds__(256) void init_kernel(int* __restrict__ fctr,
                                                   const int* __restrict__ batch,
                                                   const float* __restrict__ bl,
                                                   float* __restrict__ invc,
                                                   float* __restrict__ out,
                                                   int n, int nb) {
    int t = blockIdx.x * blockDim.x + threadIdx.x;
    if (t < 512) fctr[t] = 0;
    if (t < nb) {
        int l = 0, r = n;
        while (l < r) { int m = (l + r) >> 1; if (batch[m] < t) l = m + 1; else r = m; }
        int lo = l;
        r = n;
        while (l < r) { int m = (l + r) >> 1; if (batch[m] < t + 1) l = m + 1; else r = m; }
        invc[t] = 1.0f / fmaxf((float)(l - lo), 1.0f);
#pragma unroll
        for (int o = 0; o < 16; ++o) out[t * 16 + o] = bl[o];
    }
}

// Bucket edges into 512 fine dst-ranges (fixed capacity CAPB, base=g*CAPB).
__global__ __launch_bounds__(256) void bin512_kernel(const int* __restrict__ src,
                                                     const int* __restrict__ dst,
                                                     int* __restrict__ fctr,
                                                     int2* __restrict__ recs2,
                                                     int e, int n) {
    __shared__ int lcnt[512], gbase[512];
    int tid = threadIdx.x;
    int s0  = blockIdx.x * BINTILE;
    lcnt[tid] = 0;
    lcnt[tid + 256] = 0;
    __syncthreads();
    int dv[16], bk[16];
#pragma unroll
    for (int k = 0; k < 16; ++k) {
        int i = s0 + tid + k * 256;  // coalesced
        if (i < e) {
            dv[k] = dst[i];
            bk[k] = (int)((512LL * dv[k]) / n);
            atomicAdd(&lcnt[bk[k]], 1);
        } else {
            bk[k] = -1;
        }
    }
    __syncthreads();
#pragma unroll
    for (int j = 0; j < 2; ++j) {
        int b = tid + j * 256;
        gbase[b] = b * CAPB + atomicAdd(&fctr[b], lcnt[b]);
        lcnt[b]  = 0;  // reuse as placement counter
    }
    __syncthreads();
#pragma unroll
    for (int k = 0; k < 16; ++k) {
        if (bk[k] >= 0) {
            int i = s0 + tid + k * 256;
            int p = gbase[bk[k]] + atomicAdd(&lcnt[bk[k]], 1);
            if (p < (bk[k] + 1) * CAPB) recs2[p] = make_int2(src[i], dv[k]);
        }
    }
}

// One block per fine bucket: LDS counting sort -> dense csr, rp/dinv, then
// fused mm1 for this bucket's nodes: t1 = fp16(dinv * x W1^T).
__global__ __launch_bounds__(256) void sortfill_mm_kernel(
    const int2* __restrict__ recs2, const int* __restrict__ fctr,
    int* __restrict__ rp, float* __restrict__ dinv, int* __restrict__ csr,
    const float* __restrict__ x, const float* __restrict__ W1,
    __half* __restrict__ t1, int n) {
    __shared__ int hist[128];
    __shared__ int lofs[129];
    __shared__ int stage[CAPB];
    __shared__ int redbuf[256];
    __shared__ float xrow[98 * 64];  // 25KB
    int g   = blockIdx.x;
    int N0  = (int)(((long long)n * g + 511) / 512);
    int N1  = (int)(((long long)n * (g + 1) + 511) / 512);
    int nn  = N1 - N0;  // <= 98
    int tid = threadIdx.x;
    int lane = tid & 63;
    int wave = tid >> 6;

    int partial = 0;
    for (int j = tid; j < g; j += 256) partial += min(fctr[j], CAPB);
    redbuf[tid] = partial;
    if (tid < 128) hist[tid] = 0;
    __syncthreads();
    for (int s = 128; s > 0; s >>= 1) {
        if (tid < s) redbuf[tid] += redbuf[tid + s];
        __syncthreads();
    }
    int base = redbuf[0];
    const int2* my = recs2 + (size_t)g * CAPB;
    int total = min(fctr[g], CAPB);
    for (int i = tid; i < total; i += 256)
        atomicAdd(&hist[my[i].y - N0], 1);
    __syncthreads();
    if (tid == 0) {
        int acc = 0;
        for (int k = 0; k < nn; ++k) { lofs[k] = acc; acc += hist[k]; }
        lofs[nn] = acc;
    }
    __syncthreads();
    if (tid < 128) hist[tid] = 0;  // placement counters
    __syncthreads();
    for (int i = tid; i < total; i += 256) {
        int2 rec = my[i];
        int  li  = rec.y - N0;
        int  pos = lofs[li] + atomicAdd(&hist[li], 1);
        stage[pos] = rec.x;  // pos < total <= CAPB
    }
    __syncthreads();
    for (int j = tid; j < total; j += 256) csr[base + j] = stage[j];
    if (tid < nn) {
        rp[N0 + tid]   = base + lofs[tid];
        int deg        = lofs[tid + 1] - lofs[tid];
        dinv[N0 + tid] = rsqrtf((float)(deg + 1));
    }
    if (g == 511 && tid == 0) rp[n] = base + total;

    // ---- fused mm1 for this bucket's nodes ----
    for (int idx = tid; idx < nn * 16; idx += 256)
        ((float4*)xrow)[idx] = ((const float4*)(x + (size_t)N0 * 64))[idx];
    float4 wreg[16];
    const float4* W4 = (const float4*)(W1 + lane * 64);
#pragma unroll
    for (int q = 0; q < 16; ++q) wreg[q] = W4[q];
    __syncthreads();
    for (int li = wave; li < nn; li += 4) {
        float dv = rsqrtf((float)(lofs[li + 1] - lofs[li] + 1));
        const float4* row = (const float4*)(xrow + li * 64);
        float acc = 0.0f;
#pragma unroll
        for (int q = 0; q < 16; ++q) {
            float4 hv = row[q];  // wave-uniform -> LDS broadcast
            acc += hv.x * wreg[q].x + hv.y * wreg[q].y +
                   hv.z * wreg[q].z + hv.w * wreg[q].w;
        }
        t1[(size_t)(N0 + li) * 64 + lane] = __float2half(acc * dv);
    }
}

// Fused agg(layer k) + mm(layer k+1): 512 thr = 8 waves = 8 NODES per block,
// 1 node per WAVE (6250 blocks -> 61% occupancy per R25). Gather = R21's
// proven single-pass 4-group slice (deg/4 per group, 8-wide clamped
// mask-FMA, ~2 latency phases). shfl_xor(16,32) reduce -> grp0 writes h row
// to LDS; per-wave mm (W L1-resident, reload tolerated at this TLP; dv
// wave-uniform).
__global__ __launch_bounds__(512, 4) void aggmm_kernel(const __half* __restrict__ t,
                                                       const int* __restrict__ rp,
                                                       const int* __restrict__ cs,
                                                       const float* __restrict__ dinv,
                                                       const float* __restrict__ bias,
                                                       const float* __restrict__ W,
                                                       __half* __restrict__ tout, int n) {
    __shared__ float hs[8 * 64];  // 2KB
    int tid  = threadIdx.x;
    int lane = tid & 63;
    int wave = tid >> 6;        // 0..7 = local node
    int grp  = lane >> 4;
    int fo   = (lane & 15) << 2;
    int base = blockIdx.x * 8;
    int i    = base + wave;
    int ii   = min(i, n - 1);   // tail-block clamp; stores guarded by i<n

    int beg = rp[ii];
    int end = rp[ii + 1];
    int deg = end - beg;

    // independent early loads
    uint2 su = *(const uint2*)(t + (size_t)ii * 64 + fo);
    float dv = dinv[ii];
    float4 bv = *(const float4*)(bias + fo);

    int len = (deg + 3) >> 2;       // per-group slice
    int gb  = beg + grp * len;
    int ge  = min(gb + len, end);

    float4 aa[4];
    aa[0] = make_float4(0.f, 0.f, 0.f, 0.f);
    aa[1] = aa[0]; aa[2] = aa[0]; aa[3] = aa[0];
    for (int eb = gb; eb < ge; eb += 8) {
#pragma unroll
        for (int j = 0; j < 8; ++j) {
            int   ej = eb + j;
            int   ec = min(ej, end - 1);            // in csr bounds (loop => deg>0)
            int   sj = cs[ec];                      // unconditional load
            uint2 u  = *(const uint2*)(t + (size_t)sj * 64 + fo);
            float m  = (ej < ge) ? 1.0f : 0.0f;
            float2 f0 = __half22float2(*(const __half2*)&u.x);
            float2 f1 = __half22float2(*(const __half2*)&u.y);
            aa[j & 3].x = fmaf(m, f0.x, aa[j & 3].x);
            aa[j & 3].y = fmaf(m, f0.y, aa[j & 3].y);
            aa[j & 3].z = fmaf(m, f1.x, aa[j & 3].z);
            aa[j & 3].w = fmaf(m, f1.y, aa[j & 3].w);
        }
    }
    float4 acc;
    acc.x = (aa[0].x + aa[1].x) + (aa[2].x + aa[3].x);
    acc.y = (aa[0].y + aa[1].y) + (aa[2].y + aa[3].y);
    acc.z = (aa[0].z + aa[1].z) + (aa[2].z + aa[3].z);
    acc.w = (aa[0].w + aa[1].w) + (aa[2].w + aa[3].w);
    acc.x += __shfl_xor(acc.x, 16, 64);
    acc.y += __shfl_xor(acc.y, 16, 64);
    acc.z += __shfl_xor(acc.z, 16, 64);
    acc.w += __shfl_xor(acc.w, 16, 64);
    acc.x += __shfl_xor(acc.x, 32, 64);
    acc.y += __shfl_xor(acc.y, 32, 64);
    acc.z += __shfl_xor(acc.z, 32, 64);
    acc.w += __shfl_xor(acc.w, 32, 64);

    if (grp == 0 && i < n) {
        float2 s01 = __half22float2(*(const __half2*)&su.x);
        float2 s23 = __half22float2(*(const __half2*)&su.y);
        float4 h4;
        h4.x = fmaxf(fmaf(dv, acc.x + s01.x, bv.x), 0.0f);
        h4.y = fmaxf(fmaf(dv, acc.y + s01.y, bv.y), 0.0f);
        h4.z = fmaxf(fmaf(dv, acc.z + s23.x, bv.z), 0.0f);
        h4.w = fmaxf(fmaf(dv, acc.w + s23.y, bv.w), 0.0f);
        *(float4*)(hs + wave * 64 + fo) = h4;
    }
    __syncthreads();

    // ---- mm phase: wave computes its OWN node's output row (dv uniform) ----
    float4 wreg[16];
    const float4* W4 = (const float4*)(W + lane * 64);
#pragma unroll
    for (int q = 0; q < 16; ++q) wreg[q] = W4[q];  // L1-resident after 1st block
    if (i < n) {
        const float4* row = (const float4*)(hs + wave * 64);
        float acc2 = 0.0f;
#pragma unroll
        for (int q = 0; q < 16; ++q) {
            float4 hv = row[q];  // wave-uniform address -> LDS broadcast
            acc2 += hv.x * wreg[q].x + hv.y * wreg[q].y +
                    hv.z * wreg[q].z + hv.w * wreg[q].w;
        }
        tout[(size_t)i * 64 + lane] = __float2half(acc2 * dv);
    }
}

// Final layer (CONTROL — the 285.98 version): slice gather -> h3 on all
// lanes -> z = h3 . Wl^T chunk-parallel, xor-reduce, 16 atomicAdds of
// z*inv_cnt into bl-seeded out.
__global__ __launch_bounds__(256, 6) void aggfinal_kernel(const __half* __restrict__ t,
                                                          const int* __restrict__ rp,
                                                          const int* __restrict__ cs,
                                                          const float* __restrict__ dinv,
                                                          const float* __restrict__ bias,
                                                          const float* __restrict__ Wl,
                                                          const int* __restrict__ batch,
                                                          const float* __restrict__ invc,
                                                          float* __restrict__ out, int n) {
    int gw   = (blockIdx.x * blockDim.x + threadIdx.x) >> 6;
    int lane = threadIdx.x & 63;
    if (gw >= n) return;
    int i   = gw;
    int grp = lane >> 4;
    int fo  = (lane & 15) << 2;
    int beg = rp[i];
    int end = rp[i + 1];
    uint2 su = *(const uint2*)(t + (size_t)i * 64 + fo);
    float dv = dinv[i];
    float4 bv = *(const float4*)(bias + fo);

    int deg = end - beg;
    int len = (deg + 3) >> 2;
    int gb  = beg + grp * len;
    int ge  = min(gb + len, end);

    float4 aa[4];
    aa[0] = make_float4(0.f, 0.f, 0.f, 0.f);
    aa[1] = aa[0]; aa[2] = aa[0]; aa[3] = aa[0];
    for (int eb = gb; eb < ge; eb += 8) {
#pragma unroll
        for (int j = 0; j < 8; ++j) {
            int   ej = eb + j;
            int   ec = min(ej, end - 1);
            int   sj = cs[ec];
            uint2 u  = *(const uint2*)(t + (size_t)sj * 64 + fo);
            float m  = (ej < ge) ? 1.0f : 0.0f;
            float2 f0 = __half22float2(*(const __half2*)&u.x);
            float2 f1 = __half22float2(*(const __half2*)&u.y);
            aa[j & 3].x = fmaf(m, f0.x, aa[j & 3].x);
            aa[j & 3].y = fmaf(m, f0.y, aa[j & 3].y);
            aa[j & 3].z = fmaf(m, f1.x, aa[j & 3].z);
            aa[j & 3].w = fmaf(m, f1.y, aa[j & 3].w);
        }
    }
    float4 acc;
    acc.x = (aa[0].x + aa[1].x) + (aa[2].x + aa[3].x);
    acc.y = (aa[0].y + aa[1].y) + (aa[2].y + aa[3].y);
    acc.z = (aa[0].z + aa[1].z) + (aa[2].z + aa[3].z);
    acc.w = (aa[0].w + aa[1].w) + (aa[2].w + aa[3].w);
    acc.x += __shfl_xor(acc.x, 16, 64);
    acc.y += __shfl_xor(acc.y, 16, 64);
    acc.z += __shfl_xor(acc.z, 16, 64);
    acc.w += __shfl_xor(acc.w, 16, 64);
    acc.x += __shfl_xor(acc.x, 32, 64);
    acc.y += __shfl_xor(acc.y, 32, 64);
    acc.z += __shfl_xor(acc.z, 32, 64);
    acc.w += __shfl_xor(acc.w, 32, 64);

    // all lanes hold h3[i][4*(lane&15) .. +3]
    float2 s01 = __half22float2(*(const __half2*)&su.x);
    float2 s23 = __half22float2(*(const __half2*)&su.y);
    float4 h4;
    h4.x = fmaxf(fmaf(dv, acc.x + s01.x, bv.x), 0.0f);
    h4.y = fmaxf(fmaf(dv, acc.y + s01.y, bv.y), 0.0f);
    h4.z = fmaxf(fmaf(dv, acc.z + s23.x, bv.z), 0.0f);
    h4.w = fmaxf(fmaf(dv, acc.w + s23.y, bv.w), 0.0f);

    // z[o] = h3 . Wl[o], o = 4m + grp; lane uses only its own chunk.
    float4 wl0 = *(const float4*)(Wl + (0 * 4 + grp) * 64 + fo);
    float4 wl1 = *(const float4*)(Wl + (1 * 4 + grp) * 64 + fo);
    float4 wl2 = *(const float4*)(Wl + (2 * 4 + grp) * 64 + fo);
    float4 wl3 = *(const float4*)(Wl + (3 * 4 + grp) * 64 + fo);
    float z0 = h4.x * wl0.x + h4.y * wl0.y + h4.z * wl0.z + h4.w * wl0.w;
    float z1 = h4.x * wl1.x + h4.y * wl1.y + h4.z * wl1.z + h4.w * wl1.w;
    float z2 = h4.x * wl2.x + h4.y * wl2.y + h4.z * wl2.z + h4.w * wl2.w;
    float z3 = h4.x * wl3.x + h4.y * wl3.y + h4.z * wl3.z + h4.w * wl3.w;
#pragma unroll
    for (int s = 1; s <= 8; s <<= 1) {
        z0 += __shfl_xor(z0, s, 64);
        z1 += __shfl_xor(z1, s, 64);
        z2 += __shfl_xor(z2, s, 64);
        z3 += __shfl_xor(z3, s, 64);
    }
    int m = lane & 15;
    if (m < 4) {
        int   b  = batch[i];
        float ic = invc[b];
        float zv = (m == 0) ? z0 : (m == 1) ? z1 : (m == 2) ? z2 : z3;
        atomicAdd(out + b * 16 + (m * 4 + grp), zv * ic);
    }
}

extern "C" void kernel_launch(void* const* d_in, const int* in_sizes, int n_in,
                              void* d_out, int out_size, void* d_ws, size_t ws_size,
                              hipStream_t stream) {
    const float* x    = (const float*)d_in[0];
    const int*   ei   = (const int*)d_in[1];
    const int*   batch= (const int*)d_in[2];
    const float* W1   = (const float*)d_in[3];
    const float* b1   = (const float*)d_in[4];
    const float* W2   = (const float*)d_in[5];
    const float* b2   = (const float*)d_in[6];
    const float* W3   = (const float*)d_in[7];
    const float* b3   = (const float*)d_in[8];
    const float* Wl   = (const float*)d_in[9];
    const float* bl   = (const float*)d_in[10];
    float* out = (float*)d_out;

    int n  = in_sizes[0] / 64;   // 50000 nodes
    int e  = in_sizes[1] / 2;    // 1250000 edges
    int nb = out_size / 16;      // 512 graphs

    const int* esrc = ei;
    const int* edst = ei + e;

    char* p = (char*)d_ws;
    auto carve = [&](size_t bytes) {
        char* r = p;
        p += (bytes + 255) & ~(size_t)255;
        return r;
    };
    float*  dinv  = (float*)carve((size_t)n * 4);
    int*    rp    = (int*)  carve((size_t)(n + 1) * 4);
    int*    csr   = (int*)  carve((size_t)e * 4);
    __half* tA    = (__half*)carve((size_t)n * 64 * 2);  // t1 / t3
    __half* tB    = (__half*)carve((size_t)n * 64 * 2);  // t2
    int2*   recs2 = (int2*) carve((size_t)512 * CAPB * 8);
    int*    fctr  = (int*)  carve(512 * 4);
    float*  invc  = (float*)carve((size_t)nb * 4);

    dim3 blk(256);
    int gBIN = (e + BINTILE - 1) / BINTILE;  // 306 tiles
    int gFUS = (n + 7) / 8;                  // 8 nodes / 512-thr block (1/wave)
    int gAGG = (n + 3) / 4;                  // one node per wave (aggfinal)

    init_kernel<<<2, blk, 0, stream>>>(fctr, batch, bl, invc, out, n, nb);
    bin512_kernel<<<gBIN, blk, 0, stream>>>(esrc, edst, fctr, recs2, e, n);
    sortfill_mm_kernel<<<512, blk, 0, stream>>>(recs2, fctr, rp, dinv, csr,
                                                x, W1, tA, n);
    aggmm_kernel<<<gFUS, dim3(512), 0, stream>>>(tA, rp, csr, dinv, b1, W2, tB, n);
    aggmm_kernel<<<gFUS, dim3(512), 0, stream>>>(tB, rp, csr, dinv, b2, W3, tA, n);
    aggfinal_kernel<<<gAGG, blk, 0, stream>>>(tA, rp, csr, dinv, b3, Wl,
                                              batch, invc, out, n);
}

// Round 8
// 280.672 us; speedup vs baseline: 1.5700x; 1.4229x over previous
//
#include <hip/hip_runtime.h>
#include <hip/hip_fp16.h>

// ---------------------------------------------------------------------------
// GCN (3 layers) + global mean pool + linear, fp32 in/out, MI355X.
// t'[i] = dinv[i] * h[i] W^T; h_next[i] = relu(dinv[i]*(t'[i]+sum t'[j]) + b)
// R3-R5: scattered 4B global stores/atomics = ~32B HBM sector each. Dense only.
// R9: fp16 t (128B row = 1 L2 line), absmax 1.2e-4.
// R20/R23/R24: W-in-regs-per-wave & >8-deep HIP load windows: compiler
//   refuses (VGPR stuck ~52). ILP-window lever DEAD.
// R25: 2-pass L2 half-tiling: FAILED (loads doubled; gather is NOT miss-bound
//   -- FETCH 42MB of 160MB traffic = 74% cache-absorbed).
// R26 (diagnostic): 1-node/wave fused = 119us @ 61% occupancy. Occupancy is
//   ANTI-correlated. A/B/C matrix (R2 split 44us no-barrier / R22 fused 58.7
//   barrier 4-node-waves / R26 fused 119 barrier 1-node-waves) isolates
//   __syncthreads STRAGGLER COUPLING x wave granularity as the governor
//   (Poisson deg: block waits for max-of-8 waves; amortized at 4 nodes/wave)
//   + per-wave W reload (800MB at 50k waves).
// R27 (this round): R22 shape, barrier REMOVED. Wave w gathers nodes
//   base+4w..+3 into LDS rows 4w..4w+3 and mm reads ONLY those rows ->
//   LDS is wave-private, intra-wave ds ordering is compiler-guaranteed,
//   no block barrier needed. Waves fully decoupled.
// ---------------------------------------------------------------------------

#define CAPB 3072
#define BINTILE 4096

// fctr zero + per-graph inverse counts (binary search on sorted batch) +
// out seeded with bl (aggfinal accumulates atomically on top).
__global__ __launch_bounds__(256) void init_kernel(int* __restrict__ fctr,
                                                   const int* __restrict__ batch,
                                                   const float* __restrict__ bl,
                                                   float* __restrict__ invc,
                                                   float* __restrict__ out,
                                                   int n, int nb) {
    int t = blockIdx.x * blockDim.x + threadIdx.x;
    if (t < 512) fctr[t] = 0;
    if (t < nb) {
        int l = 0, r = n;
        while (l < r) { int m = (l + r) >> 1; if (batch[m] < t) l = m + 1; else r = m; }
        int lo = l;
        r = n;
        while (l < r) { int m = (l + r) >> 1; if (batch[m] < t + 1) l = m + 1; else r = m; }
        invc[t] = 1.0f / fmaxf((float)(l - lo), 1.0f);
#pragma unroll
        for (int o = 0; o < 16; ++o) out[t * 16 + o] = bl[o];
    }
}

// Bucket edges into 512 fine dst-ranges (fixed capacity CAPB, base=g*CAPB).
__global__ __launch_bounds__(256) void bin512_kernel(const int* __restrict__ src,
                                                     const int* __restrict__ dst,
                                                     int* __restrict__ fctr,
                                                     int2* __restrict__ recs2,
                                                     int e, int n) {
    __shared__ int lcnt[512], gbase[512];
    int tid = threadIdx.x;
    int s0  = blockIdx.x * BINTILE;
    lcnt[tid] = 0;
    lcnt[tid + 256] = 0;
    __syncthreads();
    int dv[16], bk[16];
#pragma unroll
    for (int k = 0; k < 16; ++k) {
        int i = s0 + tid + k * 256;  // coalesced
        if (i < e) {
            dv[k] = dst[i];
            bk[k] = (int)((512LL * dv[k]) / n);
            atomicAdd(&lcnt[bk[k]], 1);
        } else {
            bk[k] = -1;
        }
    }
    __syncthreads();
#pragma unroll
    for (int j = 0; j < 2; ++j) {
        int b = tid + j * 256;
        gbase[b] = b * CAPB + atomicAdd(&fctr[b], lcnt[b]);
        lcnt[b]  = 0;  // reuse as placement counter
    }
    __syncthreads();
#pragma unroll
    for (int k = 0; k < 16; ++k) {
        if (bk[k] >= 0) {
            int i = s0 + tid + k * 256;
            int p = gbase[bk[k]] + atomicAdd(&lcnt[bk[k]], 1);
            if (p < (bk[k] + 1) * CAPB) recs2[p] = make_int2(src[i], dv[k]);
        }
    }
}

// One block per fine bucket: LDS counting sort -> dense csr, rp/dinv, then
// fused mm1 for this bucket's nodes: t1 = fp16(dinv * x W1^T).
__global__ __launch_bounds__(256) void sortfill_mm_kernel(
    const int2* __restrict__ recs2, const int* __restrict__ fctr,
    int* __restrict__ rp, float* __restrict__ dinv, int* __restrict__ csr,
    const float* __restrict__ x, const float* __restrict__ W1,
    __half* __restrict__ t1, int n) {
    __shared__ int hist[128];
    __shared__ int lofs[129];
    __shared__ int stage[CAPB];
    __shared__ int redbuf[256];
    __shared__ float xrow[98 * 64];  // 25KB
    int g   = blockIdx.x;
    int N0  = (int)(((long long)n * g + 511) / 512);
    int N1  = (int)(((long long)n * (g + 1) + 511) / 512);
    int nn  = N1 - N0;  // <= 98
    int tid = threadIdx.x;
    int lane = tid & 63;
    int wave = tid >> 6;

    int partial = 0;
    for (int j = tid; j < g; j += 256) partial += min(fctr[j], CAPB);
    redbuf[tid] = partial;
    if (tid < 128) hist[tid] = 0;
    __syncthreads();
    for (int s = 128; s > 0; s >>= 1) {
        if (tid < s) redbuf[tid] += redbuf[tid + s];
        __syncthreads();
    }
    int base = redbuf[0];
    const int2* my = recs2 + (size_t)g * CAPB;
    int total = min(fctr[g], CAPB);
    for (int i = tid; i < total; i += 256)
        atomicAdd(&hist[my[i].y - N0], 1);
    __syncthreads();
    if (tid == 0) {
        int acc = 0;
        for (int k = 0; k < nn; ++k) { lofs[k] = acc; acc += hist[k]; }
        lofs[nn] = acc;
    }
    __syncthreads();
    if (tid < 128) hist[tid] = 0;  // placement counters
    __syncthreads();
    for (int i = tid; i < total; i += 256) {
        int2 rec = my[i];
        int  li  = rec.y - N0;
        int  pos = lofs[li] + atomicAdd(&hist[li], 1);
        stage[pos] = rec.x;  // pos < total <= CAPB
    }
    __syncthreads();
    for (int j = tid; j < total; j += 256) csr[base + j] = stage[j];
    if (tid < nn) {
        rp[N0 + tid]   = base + lofs[tid];
        int deg        = lofs[tid + 1] - lofs[tid];
        dinv[N0 + tid] = rsqrtf((float)(deg + 1));
    }
    if (g == 511 && tid == 0) rp[n] = base + total;

    // ---- fused mm1 for this bucket's nodes ----
    for (int idx = tid; idx < nn * 16; idx += 256)
        ((float4*)xrow)[idx] = ((const float4*)(x + (size_t)N0 * 64))[idx];
    float4 wreg[16];
    const float4* W4 = (const float4*)(W1 + lane * 64);
#pragma unroll
    for (int q = 0; q < 16; ++q) wreg[q] = W4[q];
    __syncthreads();
    for (int li = wave; li < nn; li += 4) {
        float dv = rsqrtf((float)(lofs[li + 1] - lofs[li] + 1));
        const float4* row = (const float4*)(xrow + li * 64);
        float acc = 0.0f;
#pragma unroll
        for (int q = 0; q < 16; ++q) {
            float4 hv = row[q];  // wave-uniform -> LDS broadcast
            acc += hv.x * wreg[q].x + hv.y * wreg[q].y +
                   hv.z * wreg[q].z + hv.w * wreg[q].w;
        }
        t1[(size_t)(N0 + li) * 64 + lane] = __float2half(acc * dv);
    }
}

// Fused agg(layer k) + mm(layer k+1): 512 thr = 8 waves, 32 nodes/block.
// GATHER: one node per 16-lane group (lane owns features fo..fo+3
// EXCLUSIVELY, no cross-lane reduce); 8-deep index-clamped mask-FMA -> 4
// independent nodes/wave. h rows -> LDS (wave-private rows 4w..4w+3).
// R27: NO __syncthreads -- mm reads only this wave's own rows, so LDS dep
// is intra-wave (compiler-ordered via lgkmcnt); waves fully decoupled, no
// straggler coupling.
// MM: W row per lane in 16 float4 regs (amortized over 4 rows/wave).
__global__ __launch_bounds__(512, 4) void aggmm_kernel(const __half* __restrict__ t,
                                                       const int* __restrict__ rp,
                                                       const int* __restrict__ cs,
                                                       const float* __restrict__ dinv,
                                                       const float* __restrict__ bias,
                                                       const float* __restrict__ W,
                                                       __half* __restrict__ tout, int n) {
    __shared__ float hs[32 * 64];  // 8KB, rows 4w..4w+3 private to wave w
    __shared__ float dvs[32];
    int tid  = threadIdx.x;
    int lane = tid & 63;
    int wave = tid >> 6;        // 0..7
    int g    = lane >> 4;       // group = node slot 0..3
    int fo   = (lane & 15) << 2;// lane owns features fo..fo+3
    int base = blockIdx.x * 32;
    int nl   = wave * 4 + g;    // local node 0..31
    int i    = base + nl;

    float4 a0 = make_float4(0.f, 0.f, 0.f, 0.f);
    float4 a1 = a0;
    float2 s01 = make_float2(0.f, 0.f), s23 = s01;
    float  dv = 1.0f;

    if (i < n) {
        int beg = rp[i];
        int end = rp[i + 1];
        uint2 su = *(const uint2*)(t + (size_t)i * 64 + fo);  // self row (early)
        dv = dinv[i];
        for (int eb = beg; eb < end; eb += 8) {
#pragma unroll
            for (int j = 0; j < 8; ++j) {
                int   ej = eb + j;
                int   ec = min(ej, end - 1);         // in-bounds (loop => end>beg)
                int   sj = cs[ec];                   // unconditional load
                uint2 u  = *(const uint2*)(t + (size_t)sj * 64 + fo);
                float m  = (ej < end) ? 1.0f : 0.0f;
                float2 f0 = __half22float2(*(const __half2*)&u.x);
                float2 f1 = __half22float2(*(const __half2*)&u.y);
                if (j & 1) {
                    a1.x = fmaf(m, f0.x, a1.x);
                    a1.y = fmaf(m, f0.y, a1.y);
                    a1.z = fmaf(m, f1.x, a1.z);
                    a1.w = fmaf(m, f1.y, a1.w);
                } else {
                    a0.x = fmaf(m, f0.x, a0.x);
                    a0.y = fmaf(m, f0.y, a0.y);
                    a0.z = fmaf(m, f1.x, a0.z);
                    a0.w = fmaf(m, f1.y, a0.w);
                }
            }
        }
        s01 = __half22float2(*(const __half2*)&su.x);
        s23 = __half22float2(*(const __half2*)&su.y);
    }
    if (i < n) {
        float4 bv = *(const float4*)(bias + fo);
        float4 h4;
        h4.x = fmaxf(fmaf(dv, (a0.x + a1.x) + s01.x, bv.x), 0.0f);
        h4.y = fmaxf(fmaf(dv, (a0.y + a1.y) + s01.y, bv.y), 0.0f);
        h4.z = fmaxf(fmaf(dv, (a0.z + a1.z) + s23.x, bv.z), 0.0f);
        h4.w = fmaxf(fmaf(dv, (a0.w + a1.w) + s23.y, bv.w), 0.0f);
        *(float4*)(hs + nl * 64 + fo) = h4;
        if ((lane & 15) == 0) dvs[nl] = dv;
    }
    // NO __syncthreads(): rows 4w..4w+3 and dvs[4w..4w+3] are written and
    // read only by wave w; intra-wave ds ordering handled by compiler.

    // ---- mm phase (4 rows/wave, W amortized) ----
    float4 wreg[16];
    const float4* W4 = (const float4*)(W + lane * 64);
#pragma unroll
    for (int q = 0; q < 16; ++q) wreg[q] = W4[q];
#pragma unroll
    for (int rr = 0; rr < 4; ++rr) {
        int r  = wave * 4 + rr;
        int io = base + r;
        if (io < n) {
            const float4* row = (const float4*)(hs + r * 64);
            float acc = 0.0f;
#pragma unroll
            for (int q = 0; q < 16; ++q) {
                float4 hv = row[q];  // wave-uniform address -> LDS broadcast
                acc += hv.x * wreg[q].x + hv.y * wreg[q].y +
                       hv.z * wreg[q].z + hv.w * wreg[q].w;
            }
            tout[(size_t)io * 64 + lane] = __float2half(acc * dvs[r]);
        }
    }
}

// Final layer (CONTROL — the 285.98 version): slice gather -> h3 on all
// lanes -> z = h3 . Wl^T chunk-parallel, xor-reduce, 16 atomicAdds of
// z*inv_cnt into bl-seeded out.
__global__ __launch_bounds__(256, 6) void aggfinal_kernel(const __half* __restrict__ t,
                                                          const int* __restrict__ rp,
                                                          const int* __restrict__ cs,
                                                          const float* __restrict__ dinv,
                                                          const float* __restrict__ bias,
                                                          const float* __restrict__ Wl,
                                                          const int* __restrict__ batch,
                                                          const float* __restrict__ invc,
                                                          float* __restrict__ out, int n) {
    int gw   = (blockIdx.x * blockDim.x + threadIdx.x) >> 6;
    int lane = threadIdx.x & 63;
    if (gw >= n) return;
    int i   = gw;
    int grp = lane >> 4;
    int fo  = (lane & 15) << 2;
    int beg = rp[i];
    int end = rp[i + 1];
    uint2 su = *(const uint2*)(t + (size_t)i * 64 + fo);
    float dv = dinv[i];
    float4 bv = *(const float4*)(bias + fo);

    int deg = end - beg;
    int len = (deg + 3) >> 2;
    int gb  = beg + grp * len;
    int ge  = min(gb + len, end);

    float4 aa[4];
    aa[0] = make_float4(0.f, 0.f, 0.f, 0.f);
    aa[1] = aa[0]; aa[2] = aa[0]; aa[3] = aa[0];
    for (int eb = gb; eb < ge; eb += 8) {
#pragma unroll
        for (int j = 0; j < 8; ++j) {
            int   ej = eb + j;
            int   ec = min(ej, end - 1);
            int   sj = cs[ec];
            uint2 u  = *(const uint2*)(t + (size_t)sj * 64 + fo);
            float m  = (ej < ge) ? 1.0f : 0.0f;
            float2 f0 = __half22float2(*(const __half2*)&u.x);
            float2 f1 = __half22float2(*(const __half2*)&u.y);
            aa[j & 3].x = fmaf(m, f0.x, aa[j & 3].x);
            aa[j & 3].y = fmaf(m, f0.y, aa[j & 3].y);
            aa[j & 3].z = fmaf(m, f1.x, aa[j & 3].z);
            aa[j & 3].w = fmaf(m, f1.y, aa[j & 3].w);
        }
    }
    float4 acc;
    acc.x = (aa[0].x + aa[1].x) + (aa[2].x + aa[3].x);
    acc.y = (aa[0].y + aa[1].y) + (aa[2].y + aa[3].y);
    acc.z = (aa[0].z + aa[1].z) + (aa[2].z + aa[3].z);
    acc.w = (aa[0].w + aa[1].w) + (aa[2].w + aa[3].w);
    acc.x += __shfl_xor(acc.x, 16, 64);
    acc.y += __shfl_xor(acc.y, 16, 64);
    acc.z += __shfl_xor(acc.z, 16, 64);
    acc.w += __shfl_xor(acc.w, 16, 64);
    acc.x += __shfl_xor(acc.x, 32, 64);
    acc.y += __shfl_xor(acc.y, 32, 64);
    acc.z += __shfl_xor(acc.z, 32, 64);
    acc.w += __shfl_xor(acc.w, 32, 64);

    // all lanes hold h3[i][4*(lane&15) .. +3]
    float2 s01 = __half22float2(*(const __half2*)&su.x);
    float2 s23 = __half22float2(*(const __half2*)&su.y);
    float4 h4;
    h4.x = fmaxf(fmaf(dv, acc.x + s01.x, bv.x), 0.0f);
    h4.y = fmaxf(fmaf(dv, acc.y + s01.y, bv.y), 0.0f);
    h4.z = fmaxf(fmaf(dv, acc.z + s23.x, bv.z), 0.0f);
    h4.w = fmaxf(fmaf(dv, acc.w + s23.y, bv.w), 0.0f);

    // z[o] = h3 . Wl[o], o = 4m + grp; lane uses only its own chunk.
    float4 wl0 = *(const float4*)(Wl + (0 * 4 + grp) * 64 + fo);
    float4 wl1 = *(const float4*)(Wl + (1 * 4 + grp) * 64 + fo);
    float4 wl2 = *(const float4*)(Wl + (2 * 4 + grp) * 64 + fo);
    float4 wl3 = *(const float4*)(Wl + (3 * 4 + grp) * 64 + fo);
    float z0 = h4.x * wl0.x + h4.y * wl0.y + h4.z * wl0.z + h4.w * wl0.w;
    float z1 = h4.x * wl1.x + h4.y * wl1.y + h4.z * wl1.z + h4.w * wl1.w;
    float z2 = h4.x * wl2.x + h4.y * wl2.y + h4.z * wl2.z + h4.w * wl2.w;
    float z3 = h4.x * wl3.x + h4.y * wl3.y + h4.z * wl3.z + h4.w * wl3.w;
#pragma unroll
    for (int s = 1; s <= 8; s <<= 1) {
        z0 += __shfl_xor(z0, s, 64);
        z1 += __shfl_xor(z1, s, 64);
        z2 += __shfl_xor(z2, s, 64);
        z3 += __shfl_xor(z3, s, 64);
    }
    int m = lane & 15;
    if (m < 4) {
        int   b  = batch[i];
        float ic = invc[b];
        float zv = (m == 0) ? z0 : (m == 1) ? z1 : (m == 2) ? z2 : z3;
        atomicAdd(out + b * 16 + (m * 4 + grp), zv * ic);
    }
}

extern "C" void kernel_launch(void* const* d_in, const int* in_sizes, int n_in,
                              void* d_out, int out_size, void* d_ws, size_t ws_size,
                              hipStream_t stream) {
    const float* x    = (const float*)d_in[0];
    const int*   ei   = (const int*)d_in[1];
    const int*   batch= (const int*)d_in[2];
    const float* W1   = (const float*)d_in[3];
    const float* b1   = (const float*)d_in[4];
    const float* W2   = (const float*)d_in[5];
    const float* b2   = (const float*)d_in[6];
    const float* W3   = (const float*)d_in[7];
    const float* b3   = (const float*)d_in[8];
    const float* Wl   = (const float*)d_in[9];
    const float* bl   = (const float*)d_in[10];
    float* out = (float*)d_out;

    int n  = in_sizes[0] / 64;   // 50000 nodes
    int e  = in_sizes[1] / 2;    // 1250000 edges
    int nb = out_size / 16;      // 512 graphs

    const int* esrc = ei;
    const int* edst = ei + e;

    char* p = (char*)d_ws;
    auto carve = [&](size_t bytes) {
        char* r = p;
        p += (bytes + 255) & ~(size_t)255;
        return r;
    };
    float*  dinv  = (float*)carve((size_t)n * 4);
    int*    rp    = (int*)  carve((size_t)(n + 1) * 4);
    int*    csr   = (int*)  carve((size_t)e * 4);
    __half* tA    = (__half*)carve((size_t)n * 64 * 2);  // t1 / t3
    __half* tB    = (__half*)carve((size_t)n * 64 * 2);  // t2
    int2*   recs2 = (int2*) carve((size_t)512 * CAPB * 8);
    int*    fctr  = (int*)  carve(512 * 4);
    float*  invc  = (float*)carve((size_t)nb * 4);

    dim3 blk(256);
    int gBIN = (e + BINTILE - 1) / BINTILE;  // 306 tiles
    int gFUS = (n + 31) / 32;                // 32 nodes / 512-thr block
    int gAGG = (n + 3) / 4;                  // one node per wave (aggfinal)

    init_kernel<<<2, blk, 0, stream>>>(fctr, batch, bl, invc, out, n, nb);
    bin512_kernel<<<gBIN, blk, 0, stream>>>(esrc, edst, fctr, recs2, e, n);
    sortfill_mm_kernel<<<512, blk, 0, stream>>>(recs2, fctr, rp, dinv, csr,
                                                x, W1, tA, n);
    aggmm_kernel<<<gFUS, dim3(512), 0, stream>>>(tA, rp, csr, dinv, b1, W2, tB, n);
    aggmm_kernel<<<gFUS, dim3(512), 0, stream>>>(tB, rp, csr, dinv, b2, W3, tA, n);
    aggfinal_kernel<<<gAGG, blk, 0, stream>>>(tA, rp, csr, dinv, b3, Wl,
                                              batch, invc, out, n);
}